// Round 3
// baseline (312.056 us; speedup 1.0000x reference)
//
#include <hip/hip_runtime.h>
#include <stdint.h>

#define B_DIM 8
#define N_DIM 2048
#define F_DIM 128
#define LN_EPS 1e-5f

typedef __attribute__((ext_vector_type(8))) short short8;
typedef __attribute__((ext_vector_type(4))) float floatx4;

// full RNE (used in transpose, once per element)
__device__ __forceinline__ ushort f2bf(float f) {
    union { float f; uint32_t u; } c;
    c.f = f;
    uint32_t u = c.u;
    return (ushort)((u + 0x7FFFu + ((u >> 16) & 1u)) >> 16);
}

// fast round-half-up pack of two fp32 -> packed bf16x2 (3 VALU ops)
__device__ __forceinline__ uint32_t pk2bf(float a, float b) {
    union { float f; uint32_t u; } x, y;
    x.f = a; y.f = b;
    return ((x.u + 0x8000u) >> 16) | ((y.u + 0x8000u) & 0xFFFF0000u);
}

__device__ __forceinline__ short8 pack8(float4 lo, float4 hi) {
    union { uint32_t u[4]; short8 s; } r;
    r.u[0] = pk2bf(lo.x, lo.y);
    r.u[1] = pk2bf(lo.z, lo.w);
    r.u[2] = pk2bf(hi.x, hi.y);
    r.u[3] = pk2bf(hi.z, hi.w);
    return r.s;
}

__device__ __forceinline__ short8 asw(uint4 v) {
    union { uint4 v; short8 s; } r;
    r.v = v;
    return r.s;
}

// ---------------------------------------------------------------------------
// Kernel 1: X (B, K=2048, F=128) fp32 -> Xt (B, F=128, K=2048) bf16.
// ---------------------------------------------------------------------------
__global__ __launch_bounds__(256) void k_transpose(const float* __restrict__ X,
                                                   ushort* __restrict__ Xt) {
    __shared__ ushort tile[64 * 65];
    const int t = threadIdx.x;
    const int b = blockIdx.z;
    const int k0 = blockIdx.x * 64;
    const int f0 = blockIdx.y * 64;

#pragma unroll
    for (int p = 0; p < 2; ++p) {
        int idx = p * 256 + t;
        int kk = idx >> 3;
        int ff = (idx & 7) * 8;
        const float* src = X + (((size_t)b * N_DIM) + k0 + kk) * F_DIM + f0 + ff;
        float4 v0 = *(const float4*)(src);
        float4 v1 = *(const float4*)(src + 4);
        ushort* d = tile + kk * 65 + ff;
        d[0] = f2bf(v0.x); d[1] = f2bf(v0.y); d[2] = f2bf(v0.z); d[3] = f2bf(v0.w);
        d[4] = f2bf(v1.x); d[5] = f2bf(v1.y); d[6] = f2bf(v1.z); d[7] = f2bf(v1.w);
    }
    __syncthreads();

    union U { uint4 v; ushort s[8]; };
#pragma unroll
    for (int p = 0; p < 2; ++p) {
        int idx = p * 256 + t;
        int f2 = idx >> 3;
        int kk2 = (idx & 7) * 8;
        U u;
#pragma unroll
        for (int j = 0; j < 8; ++j) u.s[j] = tile[(kk2 + j) * 65 + f2];
        *(uint4*)(Xt + (((size_t)b * F_DIM) + f0 + f2) * N_DIM + k0 + kk2) = u.v;
    }
}

// ---------------------------------------------------------------------------
// Kernel 2 (fused): H = A@X (bf16 MFMA, fp32 A converted in-register),
// then P = H@W^T + b, LayerNorm(D=128), ReLU -> fp32 out.
//
// NO barriers / NO LDS in the K-loop: each wave loads its MFMA fragments
// directly from global with a 1-deep register prefetch. 512 thr = 8 waves;
// wave w owns output cols w*16+mr; rows {mr, mr+16} of the 32-row M-tile.
// Grid 512 (XCD-swizzled: batch = bid & 7), 2 blocks/CU = 16 waves/CU.
// ---------------------------------------------------------------------------
__global__ __launch_bounds__(512) void k_fused(const float* __restrict__ A,
                                               const ushort* __restrict__ Xt,
                                               const float* __restrict__ W,
                                               const float* __restrict__ bias,
                                               const float* __restrict__ gamma,
                                               const float* __restrict__ beta,
                                               float* __restrict__ out) {
    __shared__ __align__(16) ushort Ht[32 * 136];   // 8.5 KB (H tile, bf16)
    __shared__ float Pt[32][132];                   // 16.5 KB (P tile, fp32)

    const int t = threadIdx.x;
    const int lane = t & 63;
    const int w = t >> 6;            // wave 0..7
    const int q = lane >> 4;         // 0..3
    const int mr = lane & 15;        // 0..15

    const int bid = blockIdx.x;
    const int bb = bid & 7;          // batch -> XCD affinity
    const int m0 = (bid >> 3) * 32;  // M-tile origin

    // A fragment pointers: rows m0+mr and m0+mr+16, k = q*8 + j
    const float* A0 = A + ((size_t)bb * N_DIM + m0 + mr) * N_DIM + q * 8;
    const float* A1 = A0 + (size_t)16 * N_DIM;
    // B fragment pointer: Xt row (H col) = w*16+mr, k = q*8 + j
    const ushort* Bp = Xt + ((size_t)bb * F_DIM + w * 16 + mr) * N_DIM + q * 8;

    floatx4 acc0 = {0.f, 0.f, 0.f, 0.f};
    floatx4 acc1 = {0.f, 0.f, 0.f, 0.f};

    // prime the pipeline (k-step 0)
    float4 a0l = ((const float4*)A0)[0];
    float4 a0h = ((const float4*)A0)[1];
    float4 a1l = ((const float4*)A1)[0];
    float4 a1h = ((const float4*)A1)[1];
    uint4 bv = *(const uint4*)Bp;

#pragma unroll 3
    for (int ks = 0; ks < 63; ++ks) {
        const float* pA0 = A0 + (ks + 1) * 32;
        const float* pA1 = A1 + (ks + 1) * 32;
        const ushort* pB = Bp + (ks + 1) * 32;
        // issue next k-step's loads before computing current
        float4 n0l = ((const float4*)pA0)[0];
        float4 n0h = ((const float4*)pA0)[1];
        float4 n1l = ((const float4*)pA1)[0];
        float4 n1h = ((const float4*)pA1)[1];
        uint4 nb = *(const uint4*)pB;

        short8 bf = asw(bv);
        acc0 = __builtin_amdgcn_mfma_f32_16x16x32_bf16(pack8(a0l, a0h), bf, acc0, 0, 0, 0);
        acc1 = __builtin_amdgcn_mfma_f32_16x16x32_bf16(pack8(a1l, a1h), bf, acc1, 0, 0, 0);

        a0l = n0l; a0h = n0h; a1l = n1l; a1h = n1h; bv = nb;
    }
    {
        short8 bf = asw(bv);
        acc0 = __builtin_amdgcn_mfma_f32_16x16x32_bf16(pack8(a0l, a0h), bf, acc0, 0, 0, 0);
        acc1 = __builtin_amdgcn_mfma_f32_16x16x32_bf16(pack8(a1l, a1h), bf, acc1, 0, 0, 0);
    }

    // ---- scatter H tile (bf16) to LDS.  D layout: col=lane&15 -> n (H col),
    // row = q*4+r -> m  [m89-verified]
    {
        int col = w * 16 + mr;
#pragma unroll
        for (int r = 0; r < 4; ++r) {
            union { float f; uint32_t u; } c0, c1;
            c0.f = acc0[r]; c1.f = acc1[r];
            Ht[(q * 4 + r) * 136 + col] = (ushort)((c0.u + 0x8000u + ((c0.u >> 16) & 1u) - 1u + 0x7FFFu - 0x7FFEu) >> 16);
            Ht[(16 + q * 4 + r) * 136 + col] = (ushort)((c1.u + 0x8000u) >> 16);
        }
    }
    __syncthreads();

    // ---- second GEMM: P[32x128] = Ht @ W^T.  Wave w -> P cols w*16+mr.
    floatx4 p0 = {0.f, 0.f, 0.f, 0.f};
    floatx4 p1 = {0.f, 0.f, 0.f, 0.f};
    const float* Wp = W + (w * 16 + mr) * F_DIM + q * 8;  // W row d = out col
#pragma unroll
    for (int ks = 0; ks < 4; ++ks) {
        short8 ha0 = *(const short8*)(Ht + mr * 136 + ks * 32 + q * 8);
        short8 ha1 = *(const short8*)(Ht + (mr + 16) * 136 + ks * 32 + q * 8);
        float4 wl = ((const float4*)(Wp + ks * 32))[0];
        float4 wh = ((const float4*)(Wp + ks * 32))[1];
        short8 wb = pack8(wl, wh);
        p0 = __builtin_amdgcn_mfma_f32_16x16x32_bf16(ha0, wb, p0, 0, 0, 0);
        p1 = __builtin_amdgcn_mfma_f32_16x16x32_bf16(ha1, wb, p1, 0, 0, 0);
    }

    // ---- bias add, scatter P (fp32) for row-major LN
    {
        int col = w * 16 + mr;
        float bcol = bias[col];
#pragma unroll
        for (int r = 0; r < 4; ++r) {
            Pt[q * 4 + r][col] = p0[r] + bcol;
            Pt[16 + q * 4 + r][col] = p1[r] + bcol;
        }
    }
    __syncthreads();

    // ---- LayerNorm + ReLU: 16 lanes per row, 8 values each
    const int row = t >> 4;   // 0..31
    const int seg = t & 15;   // 0..15
    float v[8];
    float s = 0.f, s2 = 0.f;
#pragma unroll
    for (int u = 0; u < 8; ++u) {
        v[u] = Pt[row][seg * 8 + u];
        s += v[u];
        s2 += v[u] * v[u];
    }
    s += __shfl_xor(s, 1);  s2 += __shfl_xor(s2, 1);
    s += __shfl_xor(s, 2);  s2 += __shfl_xor(s2, 2);
    s += __shfl_xor(s, 4);  s2 += __shfl_xor(s2, 4);
    s += __shfl_xor(s, 8);  s2 += __shfl_xor(s2, 8);
    float mu = s * (1.0f / 128.0f);
    float var = s2 * (1.0f / 128.0f) - mu * mu;
    float rs = rsqrtf(var + LN_EPS);

    float4 o[2];
    float* of = (float*)o;
#pragma unroll
    for (int u = 0; u < 8; ++u) {
        int d = seg * 8 + u;
        float y = (v[u] - mu) * rs * gamma[d] + beta[d];
        of[u] = fmaxf(y, 0.0f);
    }
    float4* dst = (float4*)(out + ((size_t)bb * N_DIM + m0 + row) * F_DIM + seg * 8);
    dst[0] = o[0];
    dst[1] = o[1];
}

// ---------------------------------------------------------------------------
extern "C" void kernel_launch(void* const* d_in, const int* in_sizes, int n_in,
                              void* d_out, int out_size, void* d_ws, size_t ws_size,
                              hipStream_t stream) {
    const float* A     = (const float*)d_in[0];
    const float* X     = (const float*)d_in[1];
    const float* W     = (const float*)d_in[2];
    const float* bias  = (const float*)d_in[3];
    const float* gamma = (const float*)d_in[4];
    const float* beta  = (const float*)d_in[5];
    float* out = (float*)d_out;

    ushort* Xt = (ushort*)d_ws;  // 4 MB bf16

    k_transpose<<<dim3(32, 2, 8), 256, 0, stream>>>(X, Xt);
    k_fused<<<dim3(512), 512, 0, stream>>>(A, Xt, W, bias, gamma, beta, out);
}

// Round 4
// 213.153 us; speedup vs baseline: 1.4640x; 1.4640x over previous
//
#include <hip/hip_runtime.h>
#include <stdint.h>

#define B_DIM 8
#define N_DIM 2048
#define F_DIM 128
#define LN_EPS 1e-5f

typedef __attribute__((ext_vector_type(8))) short short8;
typedef __attribute__((ext_vector_type(4))) float floatx4;

// full RNE fp32 -> bf16
__device__ __forceinline__ ushort f2bf(float f) {
    union { float f; uint32_t u; } c;
    c.f = f;
    uint32_t u = c.u;
    return (ushort)((u + 0x7FFFu + ((u >> 16) & 1u)) >> 16);
}

// fast round-half-up pack of two fp32 -> packed bf16x2
__device__ __forceinline__ uint32_t pk2bf(float a, float b) {
    union { float f; uint32_t u; } x, y;
    x.f = a; y.f = b;
    return ((x.u + 0x8000u) >> 16) | ((y.u + 0x8000u) & 0xFFFF0000u);
}

__device__ __forceinline__ short8 pack8(float4 lo, float4 hi) {
    union { uint32_t u[4]; short8 s; } r;
    r.u[0] = pk2bf(lo.x, lo.y);
    r.u[1] = pk2bf(lo.z, lo.w);
    r.u[2] = pk2bf(hi.x, hi.y);
    r.u[3] = pk2bf(hi.z, hi.w);
    return r.s;
}

__device__ __forceinline__ void load_lds16(const ushort* g, ushort* l) {
    __builtin_amdgcn_global_load_lds(
        (const __attribute__((address_space(1))) void*)g,
        (__attribute__((address_space(3))) void*)l,
        16, 0, 0);
}

// ---------------------------------------------------------------------------
// Kernel 1: X (B, K=2048, F=128) fp32 -> Xt (B, F=128, K=2048) bf16.
// ---------------------------------------------------------------------------
__global__ __launch_bounds__(256) void k_transpose(const float* __restrict__ X,
                                                   ushort* __restrict__ Xt) {
    __shared__ ushort tile[64 * 65];
    const int t = threadIdx.x;
    const int b = blockIdx.z;
    const int k0 = blockIdx.x * 64;
    const int f0 = blockIdx.y * 64;

#pragma unroll
    for (int p = 0; p < 2; ++p) {
        int idx = p * 256 + t;
        int kk = idx >> 3;
        int ff = (idx & 7) * 8;
        const float* src = X + (((size_t)b * N_DIM) + k0 + kk) * F_DIM + f0 + ff;
        float4 v0 = *(const float4*)(src);
        float4 v1 = *(const float4*)(src + 4);
        ushort* d = tile + kk * 65 + ff;
        d[0] = f2bf(v0.x); d[1] = f2bf(v0.y); d[2] = f2bf(v0.z); d[3] = f2bf(v0.w);
        d[4] = f2bf(v1.x); d[5] = f2bf(v1.y); d[6] = f2bf(v1.z); d[7] = f2bf(v1.w);
    }
    __syncthreads();

    union U { uint4 v; ushort s[8]; };
#pragma unroll
    for (int p = 0; p < 2; ++p) {
        int idx = p * 256 + t;
        int f2 = idx >> 3;
        int kk2 = (idx & 7) * 8;
        U u;
#pragma unroll
        for (int j = 0; j < 8; ++j) u.s[j] = tile[(kk2 + j) * 65 + f2];
        *(uint4*)(Xt + (((size_t)b * F_DIM) + f0 + f2) * N_DIM + k0 + kk2) = u.v;
    }
}

// ---------------------------------------------------------------------------
// Kernel 2 (fused): H = A@X (bf16 MFMA), P = H@W^T + b, LN(128), ReLU.
// BM=32, BN=128, BK=128.  256 thr = 4 waves; wave w owns cols w*32..+32.
// A: coalesced fp32 loads + reg pack + swizzled ds_write_b128.
// B: global_load_lds 16B from bf16 Xt (L2-hot per-XCD: batch = bid&7).
// 32 KB staged per barrier drain -> drain amortized near HBM roofline.
// LDS 65 KB -> 2 blocks/CU.
// ---------------------------------------------------------------------------
__global__ __launch_bounds__(256) void k_fused(const float* __restrict__ A,
                                               const ushort* __restrict__ Xt,
                                               const float* __restrict__ W,
                                               const float* __restrict__ bias,
                                               const float* __restrict__ gamma,
                                               const float* __restrict__ beta,
                                               float* __restrict__ out) {
    __shared__ __align__(16) ushort As[32 * 128];   //  8 KB: 32 rows x 16 chunks
    __shared__ __align__(16) ushort Bs[128 * 128];  // 32 KB: 128 rows x 16 chunks
    __shared__ __align__(16) ushort Ht[32 * 136];   // 8.5 KB
    __shared__ float Pt[32][132];                   // 16.5 KB

    const int t = threadIdx.x;
    const int lane = t & 63;
    const int w = t >> 6;            // wave 0..3
    const int q = lane >> 4;         // 0..3
    const int mr = lane & 15;        // 0..15

    const int bid = blockIdx.x;
    const int bb = bid & 7;          // batch -> XCD affinity (L2 keeps Xt slice)
    const int m0 = (bid >> 3) * 32;  // M-tile origin

    const float* Ab = A + ((size_t)bb * N_DIM + m0) * N_DIM;
    const ushort* Xb = Xt + (size_t)bb * F_DIM * N_DIM;

    // A staging map: thread t -> row (t>>3), 16 fp32 at k=(t&7)*16 (coalesced)
    const int arow = t >> 3;
    const int asw_ = arow & 7;
    const float* a_src = Ab + (size_t)arow * N_DIM + (t & 7) * 16;
    ushort* a_dst0 = As + arow * 128 + ((((t & 7) * 2) ^ asw_) * 8);
    ushort* a_dst1 = As + arow * 128 + ((((t & 7) * 2 + 1) ^ asw_) * 8);

    // B staging map: 8 glds chunks per thread; LDS slot c = p*256+t (contig
    // per wave as required), source chunk kc = (c&15) ^ (n&7), n = c>>4.
    const ushort* b_src[8];
    ushort* b_dst[8];
#pragma unroll
    for (int p = 0; p < 8; ++p) {
        int c = p * 256 + t;
        int n = c >> 4;
        int kc = (c & 15) ^ (n & 7);
        b_src[p] = Xb + (size_t)n * N_DIM + kc * 8;
        b_dst[p] = Bs + c * 8;
    }

    floatx4 acc[2][2];
#pragma unroll
    for (int i = 0; i < 2; ++i)
#pragma unroll
        for (int j = 0; j < 2; ++j) acc[i][j] = (floatx4){0.f, 0.f, 0.f, 0.f};

    for (int k0 = 0; k0 < N_DIM; k0 += 128) {
        // ---- stage: A fp32 loads first (deep HBM), then async B (L2-hot)
        float4 v0 = ((const float4*)(a_src + k0))[0];
        float4 v1 = ((const float4*)(a_src + k0))[1];
        float4 v2 = ((const float4*)(a_src + k0))[2];
        float4 v3 = ((const float4*)(a_src + k0))[3];
#pragma unroll
        for (int p = 0; p < 8; ++p) load_lds16(b_src[p] + k0, b_dst[p]);
        *(short8*)a_dst0 = pack8(v0, v1);
        *(short8*)a_dst1 = pack8(v2, v3);
        __syncthreads();

        // ---- compute: 16 MFMA / wave
#pragma unroll
        for (int ks = 0; ks < 4; ++ks) {
            short8 af[2], bf[2];
#pragma unroll
            for (int i = 0; i < 2; ++i) {
                int m = mr + i * 16;
                af[i] = *(const short8*)(As + m * 128 + (((ks * 4 + q) ^ (m & 7)) * 8));
            }
#pragma unroll
            for (int j = 0; j < 2; ++j) {
                int n = w * 32 + j * 16 + mr;
                bf[j] = *(const short8*)(Bs + n * 128 + (((ks * 4 + q) ^ (n & 7)) * 8));
            }
#pragma unroll
            for (int i = 0; i < 2; ++i)
#pragma unroll
                for (int j = 0; j < 2; ++j)
                    acc[i][j] = __builtin_amdgcn_mfma_f32_16x16x32_bf16(
                        af[i], bf[j], acc[i][j], 0, 0, 0);
        }
        __syncthreads();
    }

    // ---- scatter H tile (bf16). D layout: col=lane&15, row=q*4+reg [m89]
#pragma unroll
    for (int j = 0; j < 2; ++j) {
        int col = w * 32 + j * 16 + mr;
#pragma unroll
        for (int r = 0; r < 4; ++r) {
            Ht[(q * 4 + r) * 136 + col] = f2bf(acc[0][j][r]);
            Ht[(16 + q * 4 + r) * 136 + col] = f2bf(acc[1][j][r]);
        }
    }
    __syncthreads();

    // ---- P[32x128] = Ht @ W^T  (W fp32 from global, L1/L2-hot)
    floatx4 p[2][2];
#pragma unroll
    for (int i = 0; i < 2; ++i)
#pragma unroll
        for (int j = 0; j < 2; ++j) p[i][j] = (floatx4){0.f, 0.f, 0.f, 0.f};

#pragma unroll
    for (int ks = 0; ks < 4; ++ks) {
        short8 ha0 = *(const short8*)(Ht + mr * 136 + ks * 32 + q * 8);
        short8 ha1 = *(const short8*)(Ht + (mr + 16) * 136 + ks * 32 + q * 8);
#pragma unroll
        for (int j = 0; j < 2; ++j) {
            const float* wp = W + (w * 32 + j * 16 + mr) * F_DIM + ks * 32 + q * 8;
            short8 wb = pack8(((const float4*)wp)[0], ((const float4*)wp)[1]);
            p[0][j] = __builtin_amdgcn_mfma_f32_16x16x32_bf16(ha0, wb, p[0][j], 0, 0, 0);
            p[1][j] = __builtin_amdgcn_mfma_f32_16x16x32_bf16(ha1, wb, p[1][j], 0, 0, 0);
        }
    }

    // ---- bias add, scatter P (fp32) for row-major LN
#pragma unroll
    for (int j = 0; j < 2; ++j) {
        int col = w * 32 + j * 16 + mr;
        float bcol = bias[col];
#pragma unroll
        for (int r = 0; r < 4; ++r) {
            Pt[q * 4 + r][col] = p[0][j][r] + bcol;
            Pt[16 + q * 4 + r][col] = p[1][j][r] + bcol;
        }
    }
    __syncthreads();

    // ---- LayerNorm + ReLU: 8 lanes per row, 16 values each
    const int row = t >> 3;
    const int seg = t & 7;
    float v[16];
    float s = 0.f, s2 = 0.f;
#pragma unroll
    for (int u = 0; u < 16; ++u) {
        v[u] = Pt[row][seg * 16 + u];
        s += v[u];
        s2 += v[u] * v[u];
    }
    s += __shfl_xor(s, 1);  s2 += __shfl_xor(s2, 1);
    s += __shfl_xor(s, 2);  s2 += __shfl_xor(s2, 2);
    s += __shfl_xor(s, 4);  s2 += __shfl_xor(s2, 4);
    float mu = s * (1.0f / 128.0f);
    float var = s2 * (1.0f / 128.0f) - mu * mu;
    float rs = rsqrtf(var + LN_EPS);

    float4 o[4];
    float* of = (float*)o;
#pragma unroll
    for (int u = 0; u < 16; ++u) {
        int d = seg * 16 + u;
        float y = (v[u] - mu) * rs * gamma[d] + beta[d];
        of[u] = fmaxf(y, 0.0f);
    }
    float4* dst = (float4*)(out + ((size_t)bb * N_DIM + m0 + row) * F_DIM + seg * 16);
    dst[0] = o[0]; dst[1] = o[1]; dst[2] = o[2]; dst[3] = o[3];
}

// ---------------------------------------------------------------------------
extern "C" void kernel_launch(void* const* d_in, const int* in_sizes, int n_in,
                              void* d_out, int out_size, void* d_ws, size_t ws_size,
                              hipStream_t stream) {
    const float* A     = (const float*)d_in[0];
    const float* X     = (const float*)d_in[1];
    const float* W     = (const float*)d_in[2];
    const float* bias  = (const float*)d_in[3];
    const float* gamma = (const float*)d_in[4];
    const float* beta  = (const float*)d_in[5];
    float* out = (float*)d_out;

    ushort* Xt = (ushort*)d_ws;  // 4 MB bf16

    k_transpose<<<dim3(32, 2, 8), 256, 0, stream>>>(X, Xt);
    k_fused<<<dim3(512), 256, 0, stream>>>(A, Xt, W, bias, gamma, beta, out);
}